// Round 9
// baseline (220.526 us; speedup 1.0000x reference)
//
#include <hip/hip_runtime.h>

// DHSMoEDetector: N=16384 tokens, D=768, H=768, C=2, E=20
#define N_D 768
#define N_H 768
#define N_C 2
#define N_E 20
#define MT 128   // pad-row count for Xg tail (>= MTA)
#define MTA 64   // gemm A-tile rows
#define NT 128
#define BK 32
#define KT (N_D / BK)  // 24 K-steps
#define MAX_TILES 288
#define NCOL (N_H / NT)  // 6 column blocks
#define ROWB (N_D * 2)   // row stride in bytes (bf16)
#define W1BLKS (N_E * (N_D / 64) * (N_H / 64))  // 2880 w1-convert blocks
#define SG_TOK 64

typedef __attribute__((ext_vector_type(8))) short short8;
typedef __attribute__((ext_vector_type(4))) float f32x4;

__device__ __forceinline__ unsigned short f2bf(float f) {
  unsigned u = __builtin_bit_cast(unsigned, f);
  u += 0x7FFFu + ((u >> 16) & 1u);
  return (unsigned short)(u >> 16);
}

#define GLD_LDS16(gp, lp)                                                        \
  __builtin_amdgcn_global_load_lds(                                              \
      (const __attribute__((address_space(1))) void*)(gp),                       \
      (__attribute__((address_space(3))) void*)(lp), 16, 0, 0)

// ---------------- front: single-block histogram + scan + tile list ---------

__global__ __launch_bounds__(256) void k_front(const int* __restrict__ cidx,
                                               int* __restrict__ counts,
                                               int* __restrict__ offsets,
                                               int* __restrict__ cursor,
                                               int* __restrict__ tiles,
                                               int* __restrict__ numTiles, int n) {
  __shared__ int lc[4][N_E];
  __shared__ int tot[N_E];
  const int tid = threadIdx.x;
  const int w = tid >> 6;
  for (int k = tid; k < 4 * N_E; k += 256) ((int*)lc)[k] = 0;
  __syncthreads();
  const int4* c4 = (const int4*)cidx;
  const int nv = n >> 2;
  for (int i = tid; i < nv; i += 256) {
    int4 v = c4[i];
    int e0 = v.x < 0 ? 0 : (v.x >= N_E ? N_E - 1 : v.x);
    int e1 = v.y < 0 ? 0 : (v.y >= N_E ? N_E - 1 : v.y);
    int e2 = v.z < 0 ? 0 : (v.z >= N_E ? N_E - 1 : v.z);
    int e3 = v.w < 0 ? 0 : (v.w >= N_E ? N_E - 1 : v.w);
    atomicAdd(&lc[w][e0], 1);
    atomicAdd(&lc[w][e1], 1);
    atomicAdd(&lc[w][e2], 1);
    atomicAdd(&lc[w][e3], 1);
  }
  for (int i = (nv << 2) + tid; i < n; i += 256) {
    int e = cidx[i];
    e = e < 0 ? 0 : (e >= N_E ? N_E - 1 : e);
    atomicAdd(&lc[w][e], 1);
  }
  __syncthreads();
  if (tid < N_E) tot[tid] = lc[0][tid] + lc[1][tid] + lc[2][tid] + lc[3][tid];
  __syncthreads();
  if (tid < 64) {
    int lane = tid;
    int c = (lane < N_E) ? tot[lane] : 0;
    int nt = (c + MTA - 1) / MTA;
    int cs = c, ts = nt;
#pragma unroll
    for (int s = 1; s < 32; s <<= 1) {
      int t1 = __shfl_up(cs, s, 64);
      int t2 = __shfl_up(ts, s, 64);
      if (lane >= s) {
        cs += t1;
        ts += t2;
      }
    }
    int coff = cs - c;
    int tbase = ts - nt;
    if (lane < N_E) {
      counts[lane] = c;
      offsets[lane] = coff;
      cursor[lane] = coff;
      for (int m = 0; m < nt; ++m) {
        int t = tbase + m;
        if (t < MAX_TILES) tiles[t] = (lane << 10) | m;
      }
    }
    if (lane == N_E - 1) *numTiles = ts > MAX_TILES ? MAX_TILES : ts;
  }
}

// ---------------- mid: scatter+gather AND W1-convert in ONE dispatch -------
// (round-5 proven: the scattered gather hides under W1's streaming BW)

__global__ __launch_bounds__(256) void k_mid(
    const int* __restrict__ cidx, int* __restrict__ cursor,
    int* __restrict__ sorted, const float* __restrict__ emb,
    unsigned short* __restrict__ Xg, const float* __restrict__ W1,
    unsigned short* __restrict__ W1t, float* __restrict__ out, int n, int nbsg) {
  __shared__ float tile[64][65];
  __shared__ int lc[N_E];
  __shared__ int lbase[N_E];
  __shared__ int pos_s[SG_TOK];
  const int tid = threadIdx.x;

  if ((int)blockIdx.x >= nbsg) {
    // ---- W1 convert/transpose with XCD chunk remap ----
    int w1i = blockIdx.x - nbsg;
    int xcd = w1i & 7, ii = w1i >> 3;
    int wgid = xcd * (W1BLKS / 8) + ii;
    int e = wgid / 144;
    int rem = wgid - e * 144;
    int h0 = (rem % 12) * 64, d0 = (rem / 12) * 64;
    const float* src = W1 + (size_t)e * N_D * N_H;
    unsigned short* dst = W1t + (size_t)e * N_H * N_D;
    int tx = tid & 15, ty = tid >> 4;
#pragma unroll
    for (int s = 0; s < 4; ++s) {
      int d = s * 16 + ty;
      float4 v = *(const float4*)&src[(size_t)(d0 + d) * N_H + h0 + tx * 4];
      tile[d][tx * 4 + 0] = v.x;
      tile[d][tx * 4 + 1] = v.y;
      tile[d][tx * 4 + 2] = v.z;
      tile[d][tx * 4 + 3] = v.w;
    }
    __syncthreads();
    int px = tid & 7, py = tid >> 3;
#pragma unroll
    for (int s = 0; s < 2; ++s) {
      int h = s * 32 + py;
      short8 v;
#pragma unroll
      for (int j = 0; j < 8; ++j)
        v[j] = (short)f2bf(tile[px * 8 + j][h]);
      *(short8*)&dst[(size_t)(h0 + h) * N_D + d0 + px * 8] = v;
    }
    return;
  }

  const int nb = (n + SG_TOK - 1) / SG_TOK;
  if ((int)blockIdx.x >= nb) {
    // pad block: zero Xg rows [n, n+MT) so tail tiles read zeros; zero out[]
    ushort4 z = {0, 0, 0, 0};
    ushort4* dst = (ushort4*)(Xg + (size_t)n * N_D);
    for (int k = tid; k < MT * N_D / 4; k += 256) dst[k] = z;
    float4 zf = {0.f, 0.f, 0.f, 0.f};
    float4* of = (float4*)out;
    for (int k = tid; k < N_C * n / 4; k += 256) of[k] = zf;
    return;
  }
  const int base_tok = blockIdx.x * SG_TOK;
  if (tid < N_E) lc[tid] = 0;
  __syncthreads();
  const int i = base_tok + tid;
  int e = 0, p = 0;
  if (tid < SG_TOK && i < n) {
    e = cidx[i];
    e = e < 0 ? 0 : (e >= N_E ? N_E - 1 : e);
    p = atomicAdd(&lc[e], 1);
  }
  __syncthreads();
  if (tid < N_E) lbase[tid] = atomicAdd(&cursor[tid], lc[tid]);
  __syncthreads();
  if (tid < SG_TOK) {
    if (i < n) {
      int pos = lbase[e] + p;
      sorted[pos] = i;
      pos_s[tid] = pos;
    } else {
      pos_s[tid] = -1;
    }
  }
  __syncthreads();
  const int wid = tid >> 6, lane = tid & 63;
  int nrows = n - base_tok;
  if (nrows > SG_TOK) nrows = SG_TOK;
  for (int rr = wid; rr < nrows; rr += 4) {
    const float4* s = (const float4*)(emb + (size_t)(base_tok + rr) * N_D);
    ushort4* d = (ushort4*)(Xg + (size_t)pos_s[rr] * N_D);
#pragma unroll
    for (int p2 = 0; p2 < 3; ++p2) {
      float4 v = s[lane + p2 * 64];
      ushort4 o;
      o.x = f2bf(v.x);
      o.y = f2bf(v.y);
      o.z = f2bf(v.z);
      o.w = f2bf(v.w);
      d[lane + p2 * 64] = o;
    }
  }
}

// ---------------- fused grouped GEMM1 + relu + layer2, 64x128 tiles --------
// Latency-regime fix: MTA=64 doubles block count to ~1660 (6.5/CU) and cuts
// per-block LDS to 36KB (3 bufs) + acc to 32 AGPR, lifting the resource
// residency ceiling to 4 blocks/CU. Depth-3 pipeline: batch kt+3 issued at
// step kt, waited at step kt+3 -> prefetch distance ~2 step-periods.
// Staging per wave per batch: 1 A-group + 2 B-groups (3 gld_lds); vmcnt(6)
// at step top drains exactly the oldest batch. Chunk-major LDS groups keep
// fragment ds_read_b128 conflict-free (proven layout).

__global__ __launch_bounds__(256, 4) void k_gemm(
    const unsigned short* __restrict__ Xg, const unsigned short* __restrict__ W1t,
    const float* __restrict__ b1, const float* __restrict__ W2,
    const float* __restrict__ b2, const int* __restrict__ sorted,
    const int* __restrict__ counts, const int* __restrict__ offsets,
    const int* __restrict__ tiles, const int* __restrict__ numTiles,
    float* __restrict__ out) {
  const int nactive = *numTiles * NCOL;
  const int lin = (int)blockIdx.y * NCOL + (int)blockIdx.x;
  if (lin >= nactive) return;
  const int q = nactive >> 3, r = nactive & 7;
  const int c = lin & 7, ii = lin >> 3;
  const int wgid = (c < r ? c * (q + 1) : r * (q + 1) + (c - r) * q) + ii;
  const int tileIdx = wgid / NCOL;
  const int n0 = (wgid - tileIdx * NCOL) * NT;

  const int tv = tiles[tileIdx];
  const int e = tv >> 10;
  const int m0 = (tv & 1023) * MTA;
  const int off = offsets[e];
  const int cnt_rel = counts[e] - m0;

  __shared__ unsigned short lA[3][MTA * BK];  // 3 x 4KB
  __shared__ unsigned short lB[3][NT * BK];   // 3 x 8KB

  const int tid = threadIdx.x;
  const int wid = tid >> 6, lane = tid & 63;
  const int wr = wid >> 1, wc = wid & 1;  // wave owns rows wr*32.., cols wc*64..
  const int quad = lane >> 4, lm = lane & 15;

  // staging: wave stages A group wid (rows 16*wid..+16) and B groups
  // {2wid, 2wid+1} (rows 32*wid..+32); lane l = (row lm, k-chunk quad)
  const char* agp =
      (const char*)Xg + (size_t)(off + m0 + wid * 16 + lm) * ROWB + quad * 16;
  const char* bgp = (const char*)W1t + (size_t)e * N_H * ROWB +
                    (size_t)(n0 + wid * 32 + lm) * ROWB + quad * 16;

#define ISSUE_BATCH(kk, b)                                                       \
  do {                                                                           \
    GLD_LDS16(agp + (kk)*64, &lA[b][wid * 512]);                                 \
    GLD_LDS16(bgp + (kk)*64, &lB[b][wid * 1024]);                                \
    GLD_LDS16(bgp + 16 * ROWB + (kk)*64, &lB[b][wid * 1024 + 512]);              \
  } while (0)

  f32x4 acc[2][4] = {};

  ISSUE_BATCH(0, 0);
  ISSUE_BATCH(1, 1);
  ISSUE_BATCH(2, 2);

  // fragment elem offset within a 16-row group: quad*128 + lm*8
  const int fa = quad * 128 + lm * 8;

  for (int kt = 0; kt < KT; ++kt) {
    const int cur = kt % 3;
    asm volatile("s_waitcnt vmcnt(6)\n\ts_barrier" ::: "memory");
    short8 af[2], bfr[4];
#pragma unroll
    for (int i = 0; i < 2; ++i)
      af[i] = *(const short8*)&lA[cur][(wr * 2 + i) * 512 + fa];
#pragma unroll
    for (int j = 0; j < 4; ++j)
      bfr[j] = *(const short8*)&lB[cur][(wc * 4 + j) * 512 + fa];
    asm volatile("s_waitcnt lgkmcnt(0)\n\ts_barrier" ::: "memory");
    int kk = kt + 3;
    if (kk >= KT) kk -= KT;  // dummy re-load keeps vmcnt bookkeeping uniform
    ISSUE_BATCH(kk, cur);
#pragma unroll
    for (int i = 0; i < 2; ++i)
#pragma unroll
      for (int j = 0; j < 4; ++j)
        acc[i][j] =
            __builtin_amdgcn_mfma_f32_16x16x32_bf16(af[i], bfr[j], acc[i][j], 0, 0, 0);
  }

  // ---- fused epilogue: h = relu(acc + b1), y-partial = h * W2[e] ----
  // C/D layout: col = lm, row = quad*4 + reg
  float y0[2][4], y1[2][4];
  for (int i = 0; i < 2; ++i)
    for (int r2 = 0; r2 < 4; ++r2) y0[i][r2] = y1[i][r2] = 0.f;

  for (int j = 0; j < 4; ++j) {
    int col = n0 + wc * 64 + j * 16 + lm;
    float bias = b1[e * N_H + col];
    float2 w2 = *(const float2*)&W2[((size_t)e * N_H + col) * N_C];
    for (int i = 0; i < 2; ++i) {
      f32x4 a = acc[i][j];
      for (int r2 = 0; r2 < 4; ++r2) {
        float h = a[r2] + bias;
        h = h > 0.f ? h : 0.f;
        y0[i][r2] += h * w2.x;
        y1[i][r2] += h * w2.y;
      }
    }
  }
  for (int s = 1; s < 16; s <<= 1) {
    for (int i = 0; i < 2; ++i)
      for (int r2 = 0; r2 < 4; ++r2) {
        y0[i][r2] += __shfl_xor(y0[i][r2], s, 64);
        y1[i][r2] += __shfl_xor(y1[i][r2], s, 64);
      }
  }
  if (lm == 0) {
    const bool add_bias = (n0 == 0) && (wc == 0);
    float bb0 = add_bias ? b2[e * N_C + 0] : 0.f;
    float bb1 = add_bias ? b2[e * N_C + 1] : 0.f;
    for (int i = 0; i < 2; ++i) {
      for (int r2 = 0; r2 < 4; ++r2) {
        int mrel = wr * 32 + i * 16 + quad * 4 + r2;
        if (mrel < cnt_rel) {
          int token = sorted[off + m0 + mrel];
          atomicAdd(&out[(size_t)token * N_C + 0], y0[i][r2] + bb0);
          atomicAdd(&out[(size_t)token * N_C + 1], y1[i][r2] + bb1);
        }
      }
    }
  }
}

// ---------------- launch ----------------

extern "C" void kernel_launch(void* const* d_in, const int* in_sizes, int n_in,
                              void* d_out, int out_size, void* d_ws, size_t ws_size,
                              hipStream_t stream) {
  const float* emb = (const float*)d_in[0];
  const int* cidx = (const int*)d_in[1];
  const float* W1 = (const float*)d_in[2];
  const float* b1 = (const float*)d_in[3];
  const float* W2 = (const float*)d_in[4];
  const float* b2 = (const float*)d_in[5];
  float* out = (float*)d_out;
  const int n = in_sizes[1];

  char* ws = (char*)d_ws;
  int* counts = (int*)ws;
  int* offsets = (int*)(ws + 128);
  int* cursor = (int*)(ws + 256);
  int* numTiles = (int*)(ws + 384);
  int* tiles = (int*)(ws + 512);  // up to 288 ints, ends < 2048
  int* sorted = (int*)(ws + 2048);
  size_t sorted_bytes = ((size_t)n * 4 + 255) & ~(size_t)255;
  unsigned short* Xg = (unsigned short*)(ws + 2048 + sorted_bytes);
  int pcap = n + MT;  // zero-padded tail rows
  unsigned short* W1t = Xg + (size_t)pcap * N_D;

  // 3 dispatches, no memsets. All workspace state is rewritten every call.
  k_front<<<1, 256, 0, stream>>>(cidx, counts, offsets, cursor, tiles, numTiles, n);
  int nbsg = (n + SG_TOK - 1) / SG_TOK + 1;  // sg blocks + 1 pad/out-zero block
  k_mid<<<nbsg + W1BLKS, 256, 0, stream>>>(cidx, cursor, sorted, emb, Xg, W1, W1t,
                                           out, n, nbsg);
  k_gemm<<<dim3(NCOL, MAX_TILES), 256, 0, stream>>>(
      Xg, W1t, b1, W2, b2, sorted, counts, offsets, tiles, numTiles, out);
}

// Round 10
// 207.086 us; speedup vs baseline: 1.0649x; 1.0649x over previous
//
#include <hip/hip_runtime.h>

// DHSMoEDetector: N=16384 tokens, D=768, H=768, C=2, E=20
#define N_D 768
#define N_H 768
#define N_C 2
#define N_E 20
#define MT 128
#define NT 128
#define BK 32
#define KT (N_D / BK)  // 24
#define MAX_TILES 160
#define NCOL (N_H / NT)  // 6
#define GRPB 24576       // bytes per 16-row group: 16*768*2
#define GPE (N_H / 16)   // 48 B-groups per expert
#define W1BLKS (N_E * (N_D / 64) * (N_H / 64))  // 2880

typedef __attribute__((ext_vector_type(8))) short short8;
typedef __attribute__((ext_vector_type(4))) float f32x4;

__device__ __forceinline__ unsigned short f2bf(float f) {
  unsigned u = __builtin_bit_cast(unsigned, f);
  u += 0x7FFFu + ((u >> 16) & 1u);
  return (unsigned short)(u >> 16);
}

#define GLD_LDS16(gp, lp)                                                        \
  __builtin_amdgcn_global_load_lds(                                              \
      (const __attribute__((address_space(1))) void*)(gp),                       \
      (__attribute__((address_space(3))) void*)(lp), 16, 0, 0)

// ---------------- front: ONE block: hist + padded scan + tiles + scatter ---
// offsets[] are MT-PADDED cumulative (groups never straddle experts); pad
// slots get sorted=-1 (gather writes zero rows there). ptotal = padded total.

__global__ __launch_bounds__(256) void k_front(const int* __restrict__ cidx,
                                               int* __restrict__ counts,
                                               int* __restrict__ offsets,
                                               int* __restrict__ tiles,
                                               int* __restrict__ numTiles,
                                               int* __restrict__ ptotal,
                                               int* __restrict__ sorted, int n) {
  __shared__ int lc[4][N_E];
  __shared__ int tot[N_E];
  __shared__ int scur[N_E];
  const int tid = threadIdx.x;
  const int w = tid >> 6;
  for (int k = tid; k < 4 * N_E; k += 256) ((int*)lc)[k] = 0;
  __syncthreads();
  const int4* c4 = (const int4*)cidx;
  const int nv = n >> 2;
  for (int i = tid; i < nv; i += 256) {
    int4 v = c4[i];
    int e0 = v.x < 0 ? 0 : (v.x >= N_E ? N_E - 1 : v.x);
    int e1 = v.y < 0 ? 0 : (v.y >= N_E ? N_E - 1 : v.y);
    int e2 = v.z < 0 ? 0 : (v.z >= N_E ? N_E - 1 : v.z);
    int e3 = v.w < 0 ? 0 : (v.w >= N_E ? N_E - 1 : v.w);
    atomicAdd(&lc[w][e0], 1);
    atomicAdd(&lc[w][e1], 1);
    atomicAdd(&lc[w][e2], 1);
    atomicAdd(&lc[w][e3], 1);
  }
  for (int i = (nv << 2) + tid; i < n; i += 256) {
    int e = cidx[i];
    e = e < 0 ? 0 : (e >= N_E ? N_E - 1 : e);
    atomicAdd(&lc[w][e], 1);
  }
  __syncthreads();
  if (tid < N_E) tot[tid] = lc[0][tid] + lc[1][tid] + lc[2][tid] + lc[3][tid];
  __syncthreads();
  if (tid < 64) {
    int lane = tid;
    int c = (lane < N_E) ? tot[lane] : 0;
    int nt = (c + MT - 1) / MT;
    int pad = nt * MT;
    int ps = pad, ts = nt;
#pragma unroll
    for (int s = 1; s < 32; s <<= 1) {
      int t1 = __shfl_up(ps, s, 64);
      int t2 = __shfl_up(ts, s, 64);
      if (lane >= s) {
        ps += t1;
        ts += t2;
      }
    }
    int off = ps - pad;   // padded offset (multiple of MT)
    int tbase = ts - nt;
    if (lane < N_E) {
      counts[lane] = c;
      offsets[lane] = off;
      scur[lane] = off;
      for (int m = 0; m < nt; ++m) {
        int t = tbase + m;
        if (t < MAX_TILES) tiles[t] = (lane << 8) | m;
      }
      // pad slots -> -1 (zero rows in gather)
      for (int p = off + c; p < off + pad; ++p) sorted[p] = -1;
    }
    if (lane == N_E - 1) {
      *numTiles = ts > MAX_TILES ? MAX_TILES : ts;
      *ptotal = ps;
    }
  }
  __syncthreads();
  // scatter: any intra-expert order is valid (output keyed by token id)
  for (int i = tid; i < n; i += 256) {
    int e = cidx[i];
    e = e < 0 ? 0 : (e >= N_E ? N_E - 1 : e);
    int p = atomicAdd(&scur[e], 1);
    sorted[p] = i;
  }
}

// ---------------- mid: group-gather + W1-swizzle + out-zero, ONE dispatch --
// Gather block g: 16 sorted tokens -> one swizzled A-group, 24KB CONTIGUOUS:
//   Xs[g][kt(24)][chunk(4)][row(16)][8 bf16]  (1KB per (g,kt))
// W1 block: (E,D,H) fp32 -> W1s[e][hgroup(48)][kt(24)][chunk][row][8] bf16.
// All gemm staging loads become lane-linear 1KB streams (pre-swizzled
// global + linear LDS dest, rule #21).

__global__ __launch_bounds__(256) void k_mid(
    const int* __restrict__ sorted, const int* __restrict__ ptotal,
    const float* __restrict__ emb, unsigned short* __restrict__ Xs,
    const float* __restrict__ W1, unsigned short* __restrict__ W1s,
    float* __restrict__ out, int n, int nbg) {
  const int tid = threadIdx.x;

  if ((int)blockIdx.x < nbg) {
    // ---- group gather ----
    const int g = blockIdx.x;
    if (g * 16 >= *ptotal) return;  // beyond padded total: never read
    const int row = tid & 15;
    const int p0 = tid >> 4;  // 0..15
    const int t = sorted[g * 16 + row];
    const bool valid = t >= 0;
    const float* src = emb + (size_t)(valid ? t : 0) * N_D;
    unsigned short* dst = (unsigned short*)((char*)Xs + (size_t)g * GRPB);
#pragma unroll
    for (int it = 0; it < 6; ++it) {
      int piece = p0 + 16 * it;       // 0..95
      int kt = piece >> 2, ch = piece & 3;
      int k0 = kt * 32 + ch * 8;
      short8 v = {};
      if (valid) {
        float4 a = *(const float4*)(src + k0);
        float4 b = *(const float4*)(src + k0 + 4);
        v[0] = (short)f2bf(a.x);
        v[1] = (short)f2bf(a.y);
        v[2] = (short)f2bf(a.z);
        v[3] = (short)f2bf(a.w);
        v[4] = (short)f2bf(b.x);
        v[5] = (short)f2bf(b.y);
        v[6] = (short)f2bf(b.z);
        v[7] = (short)f2bf(b.w);
      }
      *(short8*)(dst + (size_t)kt * 512 + ch * 128 + row * 8) = v;
    }
    return;
  }

  if ((int)blockIdx.x < nbg + W1BLKS) {
    // ---- W1 convert/transpose -> swizzled groups, XCD chunk remap ----
    __shared__ float tile[64][65];
    int w1i = blockIdx.x - nbg;
    int xcd = w1i & 7, ii = w1i >> 3;
    int wgid = xcd * (W1BLKS / 8) + ii;
    int e = wgid / 144;
    int rem = wgid - e * 144;
    int h0 = (rem % 12) * 64, d0 = (rem / 12) * 64;
    const float* src = W1 + (size_t)e * N_D * N_H;
    int tx = tid & 15, ty = tid >> 4;
#pragma unroll
    for (int s = 0; s < 4; ++s) {
      int d = s * 16 + ty;
      float4 v = *(const float4*)&src[(size_t)(d0 + d) * N_H + h0 + tx * 4];
      tile[d][tx * 4 + 0] = v.x;
      tile[d][tx * 4 + 1] = v.y;
      tile[d][tx * 4 + 2] = v.z;
      tile[d][tx * 4 + 3] = v.w;
    }
    __syncthreads();
#pragma unroll
    for (int s = 0; s < 2; ++s) {
      int piece = tid + 256 * s;  // 0..511
      int g2 = piece >> 7, ktl = (piece >> 6) & 1, ch = (piece >> 4) & 3,
          row = piece & 15;
      short8 v;
#pragma unroll
      for (int j = 0; j < 8; ++j)
        v[j] = (short)f2bf(tile[ktl * 32 + ch * 8 + j][g2 * 16 + row]);
      char* dst = (char*)W1s + ((size_t)e * GPE + (h0 >> 4) + g2) * GRPB +
                  ((d0 >> 5) + ktl) * 1024 + ch * 256 + row * 16;
      *(short8*)dst = v;
    }
    return;
  }

  // ---- zero out[] ----
  float4 zf = {0.f, 0.f, 0.f, 0.f};
  float4* of = (float4*)out;
  for (int k = tid; k < N_C * n / 4; k += 256) of[k] = zf;
}

// ---------------- fused grouped GEMM1 + relu + layer2 ----------------------
// r1 proven skeleton (depth-2, vmcnt(4), 2 barriers/step, 128x128,
// launch_bounds(256,2), XCD chunk swizzle). ONLY change: staging source
// addresses are lane-linear into the pre-swizzled Xs/W1s -> each gld_lds
// reads a contiguous 1KB block instead of 16 scattered 64B rows. LDS image
// and all fragment reads byte-identical to r1.

__global__ __launch_bounds__(256, 2) void k_gemm(
    const unsigned short* __restrict__ Xs, const unsigned short* __restrict__ W1s,
    const float* __restrict__ b1, const float* __restrict__ W2,
    const float* __restrict__ b2, const int* __restrict__ sorted,
    const int* __restrict__ counts, const int* __restrict__ offsets,
    const int* __restrict__ tiles, const int* __restrict__ numTiles,
    float* __restrict__ out) {
  const int nactive = *numTiles * NCOL;
  const int lin = (int)blockIdx.y * NCOL + (int)blockIdx.x;
  if (lin >= nactive) return;
  const int q = nactive >> 3, r = nactive & 7;
  const int c = lin & 7, ii = lin >> 3;
  const int wgid = (c < r ? c * (q + 1) : r * (q + 1) + (c - r) * q) + ii;
  const int tileIdx = wgid / NCOL;
  const int n0 = (wgid - tileIdx * NCOL) * NT;

  const int tv = tiles[tileIdx];
  const int e = tv >> 8;
  const int m0 = (tv & 255) * MT;
  const int off = offsets[e];  // MT-padded -> group-aligned
  const int cnt_rel = counts[e] - m0;

  __shared__ unsigned short lA[2][MT * BK];  // 2 x 8KB
  __shared__ unsigned short lB[2][NT * BK];

  const int tid = threadIdx.x;
  const int wid = tid >> 6, lane = tid & 63;
  const int wm = (wid >> 1) * 64, wn = (wid & 1) * 64;
  const int quad = lane >> 4, lm = lane & 15;

  // staging: wave wid stages A-groups {2wid,2wid+1}, B-groups {2wid,2wid+1};
  // each gld_lds reads 1KB contiguous: lane*16B within the (group,kt) block
  const char* agp =
      (const char*)Xs + ((size_t)((off + m0) >> 4) + 2 * wid) * GRPB + lane * 16;
  const char* bgp = (const char*)W1s +
                    ((size_t)e * GPE + (n0 >> 4) + 2 * wid) * GRPB + lane * 16;
  unsigned short* lap[2] = {&lA[0][(wid * 32) * BK], &lA[1][(wid * 32) * BK]};
  unsigned short* lbp[2] = {&lB[0][(wid * 32) * BK], &lB[1][(wid * 32) * BK]};

#define ISSUE_BATCH(kk, b)                                                       \
  do {                                                                           \
    GLD_LDS16(agp + (kk)*1024, lap[b]);                                          \
    GLD_LDS16(agp + GRPB + (kk)*1024, lap[b] + 512);                             \
    GLD_LDS16(bgp + (kk)*1024, lbp[b]);                                          \
    GLD_LDS16(bgp + GRPB + (kk)*1024, lbp[b] + 512);                             \
  } while (0)

  f32x4 acc[4][4] = {};

  ISSUE_BATCH(0, 0);
  ISSUE_BATCH(1, 1);

  const int fa = quad * 128 + lm * 8;

  for (int kt = 0; kt < KT; ++kt) {
    const int cur = kt & 1;
    asm volatile("s_waitcnt vmcnt(4)\n\ts_barrier" ::: "memory");
    short8 af[4], bfr[4];
    for (int i = 0; i < 4; ++i)
      af[i] = *(const short8*)&lA[cur][((wm >> 4) + i) * 512 + fa];
    for (int j = 0; j < 4; ++j)
      bfr[j] = *(const short8*)&lB[cur][((wn >> 4) + j) * 512 + fa];
    asm volatile("s_waitcnt lgkmcnt(0)\n\ts_barrier" ::: "memory");
    int kk = kt + 2;
    if (kk >= KT) kk -= KT;  // dummy re-load keeps vmcnt bookkeeping uniform
    ISSUE_BATCH(kk, cur);
    for (int i = 0; i < 4; ++i)
      for (int j = 0; j < 4; ++j)
        acc[i][j] =
            __builtin_amdgcn_mfma_f32_16x16x32_bf16(af[i], bfr[j], acc[i][j], 0, 0, 0);
  }

  // ---- fused epilogue: h = relu(acc + b1), y-partial = h * W2[e] ----
  float y0[4][4], y1[4][4];
  for (int i = 0; i < 4; ++i)
    for (int r2 = 0; r2 < 4; ++r2) y0[i][r2] = y1[i][r2] = 0.f;

  for (int j = 0; j < 4; ++j) {
    int col = n0 + wn + j * 16 + lm;
    float bias = b1[e * N_H + col];
    float2 w2 = *(const float2*)&W2[((size_t)e * N_H + col) * N_C];
    for (int i = 0; i < 4; ++i) {
      f32x4 a = acc[i][j];
      for (int r2 = 0; r2 < 4; ++r2) {
        float h = a[r2] + bias;
        h = h > 0.f ? h : 0.f;
        y0[i][r2] += h * w2.x;
        y1[i][r2] += h * w2.y;
      }
    }
  }
  for (int s = 1; s < 16; s <<= 1) {
    for (int i = 0; i < 4; ++i)
      for (int r2 = 0; r2 < 4; ++r2) {
        y0[i][r2] += __shfl_xor(y0[i][r2], s, 64);
        y1[i][r2] += __shfl_xor(y1[i][r2], s, 64);
      }
  }
  if (lm == 0) {
    const bool add_bias = (n0 == 0) && (wn == 0);
    float bb0 = add_bias ? b2[e * N_C + 0] : 0.f;
    float bb1 = add_bias ? b2[e * N_C + 1] : 0.f;
    for (int i = 0; i < 4; ++i) {
      for (int r2 = 0; r2 < 4; ++r2) {
        int mrel = wm + i * 16 + quad * 4 + r2;
        if (mrel < cnt_rel) {
          int token = sorted[off + m0 + mrel];
          atomicAdd(&out[(size_t)token * N_C + 0], y0[i][r2] + bb0);
          atomicAdd(&out[(size_t)token * N_C + 1], y1[i][r2] + bb1);
        }
      }
    }
  }
}

// ---------------- launch ----------------

extern "C" void kernel_launch(void* const* d_in, const int* in_sizes, int n_in,
                              void* d_out, int out_size, void* d_ws, size_t ws_size,
                              hipStream_t stream) {
  const float* emb = (const float*)d_in[0];
  const int* cidx = (const int*)d_in[1];
  const float* W1 = (const float*)d_in[2];
  const float* b1 = (const float*)d_in[3];
  const float* W2 = (const float*)d_in[4];
  const float* b2 = (const float*)d_in[5];
  float* out = (float*)d_out;
  const int n = in_sizes[1];

  char* ws = (char*)d_ws;
  int* counts = (int*)ws;
  int* offsets = (int*)(ws + 128);
  int* numTiles = (int*)(ws + 384);
  int* ptotal = (int*)(ws + 388);
  int* tiles = (int*)(ws + 512);
  int* sorted = (int*)(ws + 2048);
  const int pcap = n + N_E * MT;         // padded row capacity
  const int nbg = (pcap + 15) / 16;      // gather blocks (= groups)
  size_t sorted_bytes = ((size_t)nbg * 16 * 4 + 255) & ~(size_t)255;
  unsigned short* Xs = (unsigned short*)(ws + 2048 + sorted_bytes);
  unsigned short* W1s = Xs + (size_t)nbg * 16 * N_D;

  // 3 dispatches, no memsets. All workspace state is rewritten every call.
  k_front<<<1, 256, 0, stream>>>(cidx, counts, offsets, tiles, numTiles, ptotal,
                                 sorted, n);
  k_mid<<<nbg + W1BLKS + 1, 256, 0, stream>>>(sorted, ptotal, emb, Xs, W1, W1s,
                                              out, n, nbg);
  k_gemm<<<dim3(NCOL, MAX_TILES), 256, 0, stream>>>(
      Xs, W1s, b1, W2, b2, sorted, counts, offsets, tiles, numTiles, out);
}